// Round 6
// baseline (469.720 us; speedup 1.0000x reference)
//
#include <hip/hip_runtime.h>
#include <hip/hip_bf16.h>

#define B_    8
#define C_    192
#define H_    128
#define W_    128
#define HW_   16384
#define HEADS 4
#define S_    48
#define EPS_  1e-5f

typedef __hip_bfloat16 bf16;
typedef unsigned short u16;
typedef __attribute__((ext_vector_type(8))) short short8;
typedef __attribute__((ext_vector_type(4))) short short4v;
typedef __attribute__((ext_vector_type(4))) float f32x4;
typedef __attribute__((ext_vector_type(8))) u16 u16x8;
typedef __attribute__((ext_vector_type(4))) u16 u16x4;
typedef __attribute__((ext_vector_type(2))) u16 u16x2;

// Subtiled bf16 layout for MFMA-consumed tensors (xn, attout):
//   element (b, c, p) at  b*C*HW + (p>>4)*3072 + (c>>3)*128 + (p&15)*8 + (c&7)
// -> an 8-channel octet at one position is 16B contiguous (direct short8
//    MFMA B-fragment); 16 lanes x 4 quads read 1KB fully coalesced.

__device__ inline float ld(const bf16* p)  { return __bfloat162float(*p); }
__device__ inline void  st(float* p, float v) { *p = v; }
__device__ inline void  st(bf16* p, float v)  { *p = __float2bfloat16(v); }
__device__ inline float b2f(u16 u) {
  unsigned v = (unsigned)u << 16;
  return __builtin_bit_cast(float, v);
}
__device__ inline u16 f2b(float f) {
  return __builtin_bit_cast(u16, __float2bfloat16(f));
}

// ---------------------------------------------------------------------------
__global__ __launch_bounds__(256) void zero_kernel(float* p, int n) {
  int i = blockIdx.x * 256 + threadIdx.x;
  if (i < n) p[i] = 0.f;
}

// ---------------------------------------------------------------------------
// LayerNorm over channel axis, one-pass, writes SUBTILED xn.
// ---------------------------------------------------------------------------
__global__ __launch_bounds__(256) void ln_kernel(
    const float* __restrict__ x, const float* __restrict__ lw,
    const float* __restrict__ lb, bf16* __restrict__ xn) {
  __shared__ float4 sS[8][32];
  __shared__ float4 sQ[8][32];
  int tid = threadIdx.x;
  int g = tid >> 5, q = tid & 31;          // channel group, position quad
  int blk = blockIdx.x;                    // 0 .. B*HW/128 - 1
  int b = blk >> 7;                        // 128 blocks per image
  int pos = (blk & 127) * 128 + q * 4;
  const float* xp = x + (size_t)b * C_ * HW_ + pos;

  float4 v[3][8];
  float s0 = 0.f, s1 = 0.f, s2 = 0.f, s3 = 0.f;
  float q0 = 0.f, q1 = 0.f, q2 = 0.f, q3 = 0.f;
#pragma unroll
  for (int t = 0; t < 3; t++)
#pragma unroll
    for (int ci = 0; ci < 8; ci++) {
      int c = t * 64 + g * 8 + ci;
      float4 f = *(const float4*)&xp[(size_t)c * HW_];
      v[t][ci] = f;
      s0 += f.x; s1 += f.y; s2 += f.z; s3 += f.w;
      q0 += f.x * f.x; q1 += f.y * f.y; q2 += f.z * f.z; q3 += f.w * f.w;
    }
  sS[g][q] = make_float4(s0, s1, s2, s3);
  sQ[g][q] = make_float4(q0, q1, q2, q3);
  __syncthreads();

  float S[4] = {}, Qs[4] = {};
#pragma unroll
  for (int gg = 0; gg < 8; gg++) {
    float4 a = sS[gg][q];
    float4 bq = sQ[gg][q];
    S[0] += a.x;  S[1] += a.y;  S[2] += a.z;  S[3] += a.w;
    Qs[0] += bq.x; Qs[1] += bq.y; Qs[2] += bq.z; Qs[3] += bq.w;
  }
  float mu[4], r[4];
#pragma unroll
  for (int i = 0; i < 4; i++) {
    mu[i] = S[i] * (1.0f / C_);
    r[i] = rsqrtf(Qs[i] * (1.0f / C_) - mu[i] * mu[i] + EPS_);
  }

  u16* base = (u16*)xn + (size_t)b * C_ * HW_ +
              (size_t)((blk & 127) * 8 + (q >> 2)) * 3072;
#pragma unroll
  for (int t = 0; t < 3; t++) {
#pragma unroll
    for (int j = 0; j < 4; j++) {
      u16x8 o8;
#pragma unroll
      for (int ci = 0; ci < 8; ci++) {
        int c = t * 64 + g * 8 + ci;
        float xv = (j == 0) ? v[t][ci].x : (j == 1) ? v[t][ci].y
                 : (j == 2) ? v[t][ci].z : v[t][ci].w;
        o8[ci] = f2b((xv - mu[j]) * r[j] * lw[c] + lb[c]);
      }
      *(u16x8*)&base[(t * 8 + g) * 128 + ((q & 3) * 4 + j) * 8] = o8;
    }
  }
}

// ---------------------------------------------------------------------------
// Single pointwise conv via MFMA, SUBTILED input (used for V and final proj).
// ---------------------------------------------------------------------------
#define SWR 200
template <bool RES, typename OutT>
__global__ __launch_bounds__(256) void pw_mfma_kernel(
    const bf16* __restrict__ in, const float* __restrict__ wt,
    const float* __restrict__ bias, const bf16* __restrict__ residual,
    OutT* __restrict__ out) {
  __shared__ __align__(16) u16 sW[64 * SWR];
  int tid = threadIdx.x;
  int posBase = blockIdx.x * 256;
  int oBase = blockIdx.y * 64;
  int b = blockIdx.z;
  int wv = tid >> 6, lane = tid & 63;
  int quad = lane >> 4, l15 = lane & 15;

#pragma unroll
  for (int i = 0; i < 12; i++) {
    int u = (tid + i * 256) * 4;          // element index in 64x192
    int rr = u / 192, cc = u % 192;
    float4 f = *(const float4*)&wt[(size_t)(oBase + rr) * 192 + cc];
    ushort4 hv;
    hv.x = f2b(f.x); hv.y = f2b(f.y); hv.z = f2b(f.z); hv.w = f2b(f.w);
    *(ushort4*)&sW[rr * SWR + cc] = hv;
  }

  const u16* xb = (const u16*)in + (size_t)b * C_ * HW_ +
                  (size_t)((posBase >> 4) + wv * 4) * 3072 + quad * 128 + l15 * 8;

  short8 bf[2][4];
#pragma unroll
  for (int nt = 0; nt < 4; nt++)
    bf[0][nt] = *(const short8*)&xb[nt * 3072];

  __syncthreads();                         // sW ready

  f32x4 acc[4][4] = {};
#pragma unroll
  for (int kc = 0; kc < 6; kc++) {
    if (kc < 5) {
#pragma unroll
      for (int nt = 0; nt < 4; nt++)
        bf[(kc + 1) & 1][nt] =
            *(const short8*)&xb[nt * 3072 + (kc + 1) * 512];
    }
    short8 afrag[4];
#pragma unroll
    for (int mt = 0; mt < 4; mt++)
      afrag[mt] = *(const short8*)&sW[(mt * 16 + l15) * SWR + kc * 32 + quad * 8];
#pragma unroll
    for (int nt = 0; nt < 4; nt++)
#pragma unroll
      for (int mt = 0; mt < 4; mt++)
        acc[mt][nt] = __builtin_amdgcn_mfma_f32_16x16x32_bf16(
            afrag[mt], bf[kc & 1][nt], acc[mt][nt], 0, 0, 0);
  }

  const u16* rb = nullptr;
  if (RES)
    rb = (const u16*)residual + (size_t)b * C_ * HW_ +
         (size_t)((posBase >> 4) + wv * 4) * 3072 + l15 * 8;
#pragma unroll
  for (int mt = 0; mt < 4; mt++) {
#pragma unroll
    for (int r = 0; r < 4; r++) {
      int o = oBase + mt * 16 + quad * 4 + r;
      float bs = bias[o];
      size_t rowoff = ((size_t)b * C_ + o) * HW_;
#pragma unroll
      for (int nt = 0; nt < 4; nt++) {
        int p = posBase + wv * 64 + nt * 16 + l15;
        float val = acc[mt][nt][r] + bs;
        if (RES) val += b2f(rb[nt * 3072 + (o >> 3) * 128 + (o & 7)]);
        st(out + rowoff + p, val);
      }
    }
  }
}

// ---------------------------------------------------------------------------
// FUSED Q+K pointwise conv: both weight matrices applied to the SAME
// B-fragments -> each global short8 load feeds 8 MFMAs instead of 4.
// acc = 2x[4][4] f32x4 (128 VGPR); __launch_bounds__(256,2) caps at 256.
// ---------------------------------------------------------------------------
__global__ __launch_bounds__(256, 2) void pw2_mfma_kernel(
    const bf16* __restrict__ in,
    const float* __restrict__ wq, const float* __restrict__ bq,
    const float* __restrict__ wk, const float* __restrict__ bk,
    bf16* __restrict__ outq, bf16* __restrict__ outk) {
  __shared__ __align__(16) u16 sWq[64 * SWR];
  __shared__ __align__(16) u16 sWk[64 * SWR];
  int tid = threadIdx.x;
  int posBase = blockIdx.x * 256;
  int oBase = blockIdx.y * 64;
  int b = blockIdx.z;
  int wv = tid >> 6, lane = tid & 63;
  int quad = lane >> 4, l15 = lane & 15;

  // ---- stage both W slices (fp32 -> bf16) ----
#pragma unroll
  for (int i = 0; i < 12; i++) {
    int u = (tid + i * 256) * 4;
    int rr = u / 192, cc = u % 192;
    float4 fq = *(const float4*)&wq[(size_t)(oBase + rr) * 192 + cc];
    float4 fk = *(const float4*)&wk[(size_t)(oBase + rr) * 192 + cc];
    ushort4 hq, hk;
    hq.x = f2b(fq.x); hq.y = f2b(fq.y); hq.z = f2b(fq.z); hq.w = f2b(fq.w);
    hk.x = f2b(fk.x); hk.y = f2b(fk.y); hk.z = f2b(fk.z); hk.w = f2b(fk.w);
    *(ushort4*)&sWq[rr * SWR + cc] = hq;
    *(ushort4*)&sWk[rr * SWR + cc] = hk;
  }

  const u16* xb = (const u16*)in + (size_t)b * C_ * HW_ +
                  (size_t)((posBase >> 4) + wv * 4) * 3072 + quad * 128 + l15 * 8;

  short8 bf[2][4];
#pragma unroll
  for (int nt = 0; nt < 4; nt++)
    bf[0][nt] = *(const short8*)&xb[nt * 3072];

  __syncthreads();                         // sW ready

  f32x4 accq[4][4] = {}, acck[4][4] = {};
#pragma unroll
  for (int kc = 0; kc < 6; kc++) {
    if (kc < 5) {
#pragma unroll
      for (int nt = 0; nt < 4; nt++)
        bf[(kc + 1) & 1][nt] =
            *(const short8*)&xb[nt * 3072 + (kc + 1) * 512];
    }
    short8 afq[4], afk[4];
#pragma unroll
    for (int mt = 0; mt < 4; mt++) {
      afq[mt] = *(const short8*)&sWq[(mt * 16 + l15) * SWR + kc * 32 + quad * 8];
      afk[mt] = *(const short8*)&sWk[(mt * 16 + l15) * SWR + kc * 32 + quad * 8];
    }
#pragma unroll
    for (int nt = 0; nt < 4; nt++)
#pragma unroll
      for (int mt = 0; mt < 4; mt++) {
        accq[mt][nt] = __builtin_amdgcn_mfma_f32_16x16x32_bf16(
            afq[mt], bf[kc & 1][nt], accq[mt][nt], 0, 0, 0);
        acck[mt][nt] = __builtin_amdgcn_mfma_f32_16x16x32_bf16(
            afk[mt], bf[kc & 1][nt], acck[mt][nt], 0, 0, 0);
      }
  }

  // ---- epilogues: D row = quad*4 + reg, col = l15; NCHW outputs ----
#pragma unroll
  for (int mt = 0; mt < 4; mt++) {
#pragma unroll
    for (int r = 0; r < 4; r++) {
      int o = oBase + mt * 16 + quad * 4 + r;
      float bsq = bq[o], bsk = bk[o];
      size_t rowoff = ((size_t)b * C_ + o) * HW_;
#pragma unroll
      for (int nt = 0; nt < 4; nt++) {
        int p = posBase + wv * 64 + nt * 16 + l15;
        st(outq + rowoff + p, accq[mt][nt][r] + bsq);
        st(outk + rowoff + p, acck[mt][nt][r] + bsk);
      }
    }
  }
}

// ---------------------------------------------------------------------------
// Depthwise 3x3, SAME zero pad, TWO tensors in one launch (blockIdx.y picks).
// ---------------------------------------------------------------------------
__global__ __launch_bounds__(256) void dw2_kernel(
    const bf16* __restrict__ inA, const float* __restrict__ w9A,
    const float* __restrict__ biasA, bf16* __restrict__ outA,
    const bf16* __restrict__ inB, const float* __restrict__ w9B,
    const float* __restrict__ biasB, bf16* __restrict__ outB) {
  __shared__ __align__(16) u16 sT[18 * 128];
  const bf16* in = blockIdx.y ? inB : inA;
  const float* w9 = blockIdx.y ? w9B : w9A;
  const float* bias = blockIdx.y ? biasB : biasA;
  bf16* out = blockIdx.y ? outB : outA;

  int blk = blockIdx.x;                 // B*C*8
  int bc = blk >> 3;
  int h0 = (blk & 7) * 16;
  int c = bc % C_;
  const u16* ip = (const u16*)in + (size_t)bc * HW_;
  int tid = threadIdx.x;

  for (int ch = tid; ch < 288; ch += 256) {
    int r = ch >> 4, g = ch & 15;
    int gh = h0 - 1 + r;
    u16x8 val = {};
    if (gh >= 0 && gh < H_) val = *(const u16x8*)&ip[gh * 128 + g * 8];
    *(u16x8*)&sT[r * 128 + g * 8] = val;
  }
  __syncthreads();

  int r_o = tid >> 4, g = tid & 15;
  const float* wp = w9 + c * 9;
  float acc[8];
#pragma unroll
  for (int j = 0; j < 8; j++) acc[j] = bias[c];
#pragma unroll
  for (int k = 0; k < 3; k++) {
    int rr = r_o + k;
    u16x8 mid = *(const u16x8*)&sT[rr * 128 + g * 8];
    float m[8];
#pragma unroll
    for (int j = 0; j < 8; j++) m[j] = b2f(mid[j]);
    float lv = g ? b2f(sT[rr * 128 + g * 8 - 1]) : 0.f;
    float rv = (g < 15) ? b2f(sT[rr * 128 + g * 8 + 8]) : 0.f;
    float wl = wp[k * 3], wc = wp[k * 3 + 1], wr = wp[k * 3 + 2];
#pragma unroll
    for (int j = 0; j < 8; j++) {
      float left  = (j == 0) ? lv : m[j - 1];
      float right = (j == 7) ? rv : m[j + 1];
      acc[j] += wl * left + wc * m[j] + wr * right;
    }
  }
  u16x8 o;
#pragma unroll
  for (int j = 0; j < 8; j++) o[j] = f2b(acc[j]);
  *(u16x8*)((u16*)out + (size_t)bc * HW_ + (h0 + r_o) * 128 + g * 8) = o;
}

// ---------------------------------------------------------------------------
// Depthwise 3x3 with TRANSPOSED spatial output: out[bc, w*H + h] = conv(h,w).
// Used for V only (makes attout land in final order; transpose deleted).
// ---------------------------------------------------------------------------
__global__ __launch_bounds__(256) void dwt_kernel(
    const bf16* __restrict__ in, const float* __restrict__ w9,
    const float* __restrict__ bias, bf16* __restrict__ out) {
  __shared__ __align__(16) u16 sIn[130 * 32];
  int blk = blockIdx.x;                 // B*C*8
  int bc = blk >> 3;
  int w0 = (blk & 7) * 16;
  int c = bc % C_;
  const u16* ip = (const u16*)in + (size_t)bc * HW_;
  int tid = threadIdx.x;

  for (int idx = tid; idx < 520; idx += 256) {
    int r = idx >> 2, seg = idx & 3;
    int h = r - 1;
    int w = w0 - 8 + seg * 8;
    u16x8 val = {};
    if (h >= 0 && h < H_ && w >= 0 && w < W_)
      val = *(const u16x8*)&ip[h * W_ + w];
    int colp = (seg * 8) ^ (((r >> 3) & 3) << 4);
    *(u16x8*)&sIn[r * 32 + colp] = val;
  }
  __syncthreads();

  int wl = tid & 15, ho = tid >> 4;     // w = w0+wl, h = ho*8 .. ho*8+7
  const float* wp = w9 + c * 9;
  float wk[9];
#pragma unroll
  for (int i = 0; i < 9; i++) wk[i] = wp[i];
  float bs = bias[c];
  float acc[8];
#pragma unroll
  for (int j = 0; j < 8; j++) acc[j] = bs;
#pragma unroll
  for (int k = 0; k < 10; k++) {
    int r = ho * 8 + k;                 // staged row = input h + 1
    int swz = ((r >> 3) & 3) << 4;
    float lv = b2f(sIn[r * 32 + ((wl + 7) ^ swz)]);
    float mv = b2f(sIn[r * 32 + ((wl + 8) ^ swz)]);
    float rv = b2f(sIn[r * 32 + ((wl + 9) ^ swz)]);
#pragma unroll
    for (int kh = 0; kh < 3; kh++) {
      int j = k - kh;                   // output row index
      if (j >= 0 && j < 8)
        acc[j] += wk[kh * 3] * lv + wk[kh * 3 + 1] * mv + wk[kh * 3 + 2] * rv;
    }
  }
  u16x8 o;
#pragma unroll
  for (int j = 0; j < 8; j++) o[j] = f2b(acc[j]);
  *(u16x8*)((u16*)out + (size_t)bc * HW_ + (w0 + wl) * H_ + ho * 8) = o;
}

// ---------------------------------------------------------------------------
// Gram via MFMA, no LDS staging (pos contiguous for both operands).
// logits[bh][sk][sq] = sum_pos K[sk,pos]*Q[sq,pos]
// ---------------------------------------------------------------------------
__global__ __launch_bounds__(256) void gram_mfma_kernel(
    const bf16* __restrict__ Q, const bf16* __restrict__ K,
    float* __restrict__ logits) {
  __shared__ float sP[4][S_ * S_];
  int bh = blockIdx.y;
  int b = bh >> 2, hd = bh & 3;
  int tid = threadIdx.x;
  int wv = tid >> 6, lane = tid & 63;
  int quad = lane >> 4, l15 = lane & 15;
  const u16* Qb = (const u16*)Q + ((size_t)b * C_ + hd * S_) * HW_;
  const u16* Kb = (const u16*)K + ((size_t)b * C_ + hd * S_) * HW_;
  int pbase = blockIdx.x * 1024 + wv * 256 + quad * 8;

  f32x4 acc[3][3] = {};
#pragma unroll
  for (int t = 0; t < 8; t++) {
    int p = pbase + t * 32;
    short8 a[3], bb[3];
#pragma unroll
    for (int mi = 0; mi < 3; mi++)
      a[mi] = *(const short8*)&Kb[(size_t)(mi * 16 + l15) * HW_ + p];
#pragma unroll
    for (int ni = 0; ni < 3; ni++)
      bb[ni] = *(const short8*)&Qb[(size_t)(ni * 16 + l15) * HW_ + p];
#pragma unroll
    for (int mi = 0; mi < 3; mi++)
#pragma unroll
      for (int ni = 0; ni < 3; ni++)
        acc[mi][ni] = __builtin_amdgcn_mfma_f32_16x16x32_bf16(
            a[mi], bb[ni], acc[mi][ni], 0, 0, 0);
  }

#pragma unroll
  for (int mi = 0; mi < 3; mi++)
#pragma unroll
    for (int r = 0; r < 4; r++) {
      int sk = mi * 16 + quad * 4 + r;
#pragma unroll
      for (int ni = 0; ni < 3; ni++)
        sP[wv][sk * S_ + ni * 16 + l15] = acc[mi][ni][r];
    }
  __syncthreads();

  float* lp = logits + (size_t)bh * S_ * S_;
  for (int e = tid; e < S_ * S_; e += 256)
    atomicAdd(&lp[e], sP[0][e] + sP[1][e] + sP[2][e] + sP[3][e]);
}

// ---------------------------------------------------------------------------
// Softmax over last axis (sq), one thread per (b,hd,sk) row.
// ---------------------------------------------------------------------------
__global__ __launch_bounds__(256) void softmax_kernel(
    const float* __restrict__ logits, const float* __restrict__ alpha,
    float* __restrict__ att) {
  int row = blockIdx.x * 256 + threadIdx.x;   // 0..1535
  if (row >= B_ * HEADS * S_) return;
  float inv_a = 1.0f / alpha[0];
  const float* lp = logits + (size_t)row * S_;
  float v[S_];
  float m = -1e30f;
  for (int i = 0; i < S_; i++) {
    v[i] = lp[i] * inv_a;
    m = fmaxf(m, v[i]);
  }
  float s = 0.f;
  for (int i = 0; i < S_; i++) { v[i] = expf(v[i] - m); s += v[i]; }
  float inv_s = 1.0f / s;
  float* ap = att + (size_t)row * S_;
  for (int i = 0; i < S_; i++) ap[i] = v[i] * inv_s;
}

// ---------------------------------------------------------------------------
// att-weighted V via MFMA; output written SUBTILED (final-pw input layout).
// ---------------------------------------------------------------------------
#define AVP 264   // sV pitch in u16 (multiple of 8 -> 16B-aligned rows)
#define ATP 72    // sAtt pitch in u16 (144B rows, 16B aligned)
__global__ __launch_bounds__(256) void av_mfma_kernel(
    const bf16* __restrict__ V, const float* __restrict__ att,
    bf16* __restrict__ out) {
  __shared__ __align__(16) u16 sV[64 * AVP];   // [s 0..63][pos 0..255]
  __shared__ __align__(16) u16 sA[48 * ATP];   // [q 0..47][s 0..63]
  int bh = blockIdx.y;
  int b = bh >> 2, hd = bh & 3;
  int p0 = blockIdx.x * 256;
  int tid = threadIdx.x;
  int wv = tid >> 6, lane = tid & 63;
  int quad = lane >> 4, l15 = lane & 15;
  const u16* Vb = (const u16*)V + ((size_t)b * C_ + hd * S_) * HW_ + p0;
  const float* ap = att + (size_t)bh * S_ * S_;

#pragma unroll
  for (int i = 0; i < 6; i++) {
    int e = tid + i * 256;               // 0..1535 over 48 s x 32 pos-octets
    int s = e >> 5, p8 = (e & 31) * 8;
    u16x8 v8 = *(const u16x8*)&Vb[(size_t)s * HW_ + p8];
    *(u16x8*)&sV[s * AVP + p8] = v8;
  }
  {
    unsigned* zp = (unsigned*)&sV[48 * AVP];
    for (int e = tid; e < 16 * AVP / 2; e += 256) zp[e] = 0;
  }
  for (int e = tid; e < S_ * S_; e += 256) {
    int q = e % S_, s = e / S_;          // ap[s*48+q] == ap[e]
    sA[q * ATP + s] = f2b(ap[e]);
  }
  for (int e = tid; e < S_ * 16; e += 256) {
    int q = e >> 4, s = 48 + (e & 15);
    sA[q * ATP + s] = 0;
  }
  __syncthreads();

  f32x4 acc[3][4] = {};
#pragma unroll
  for (int kc = 0; kc < 2; kc++) {
    short8 afrag[3];
#pragma unroll
    for (int mt = 0; mt < 3; mt++)
      afrag[mt] = *(const short8*)&sA[(mt * 16 + l15) * ATP + kc * 32 + quad * 8];
#pragma unroll
    for (int nt = 0; nt < 4; nt++) {
      int p = wv * 64 + nt * 16 + l15;
      short8 bfrag;
#pragma unroll
      for (int j = 0; j < 8; j++)
        bfrag[j] = (short)sV[(kc * 32 + quad * 8 + j) * AVP + p];
#pragma unroll
      for (int mt = 0; mt < 3; mt++)
        acc[mt][nt] = __builtin_amdgcn_mfma_f32_16x16x32_bf16(
            afrag[mt], bfrag, acc[mt][nt], 0, 0, 0);
    }
  }

  u16* ob = (u16*)out + (size_t)b * C_ * HW_ + (size_t)(p0 >> 4) * 3072;
#pragma unroll
  for (int mt = 0; mt < 3; mt++)
#pragma unroll
    for (int r = 0; r < 4; r++) {
      int ql = mt * 16 + quad * 4 + r;
      int ch = hd * S_ + ql;
      int cb = (ch >> 3) * 128 + (ch & 7);
#pragma unroll
      for (int nt = 0; nt < 4; nt++)
        ob[(size_t)(wv * 4 + nt) * 3072 + cb + l15 * 8] = f2b(acc[mt][nt][r]);
    }
}

// ---------------------------------------------------------------------------
extern "C" void kernel_launch(void* const* d_in, const int* in_sizes, int n_in,
                              void* d_out, int out_size, void* d_ws, size_t ws_size,
                              hipStream_t stream) {
  const float* x      = (const float*)d_in[0];
  const float* ln_w   = (const float*)d_in[1];
  const float* ln_b   = (const float*)d_in[2];
  const float* q_pw_w = (const float*)d_in[3];
  const float* q_pw_b = (const float*)d_in[4];
  const float* q_dw_w = (const float*)d_in[5];
  const float* q_dw_b = (const float*)d_in[6];
  const float* k_pw_w = (const float*)d_in[7];
  const float* k_pw_b = (const float*)d_in[8];
  const float* k_dw_w = (const float*)d_in[9];
  const float* k_dw_b = (const float*)d_in[10];
  const float* v_pw_w = (const float*)d_in[11];
  const float* v_pw_b = (const float*)d_in[12];
  const float* v_dw_w = (const float*)d_in[13];
  const float* v_dw_b = (const float*)d_in[14];
  const float* f_w    = (const float*)d_in[15];
  const float* f_b    = (const float*)d_in[16];
  const float* alpha  = (const float*)d_in[17];
  float* out = (float*)d_out;

  size_t N = (size_t)B_ * C_ * HW_;           // 25,165,824
  bf16* xn   = (bf16*)d_ws;                   // LayerNorm output, SUBTILED
  bf16* tmp  = xn + N;                        // Pq, then Pv, then attout
  bf16* A    = tmp + N;                       // Pk, then attout... (see flow)
  bf16* A2   = A + N;                         // Vd (transposed V)
  float* logits = (float*)(A2 + N);           // [32][48][48]
  float* att    = logits + (size_t)B_ * HEADS * S_ * S_;
  bf16* Qd = (bf16*)d_out;                    // d_out scratch: Qd | Kd (2N u16)
  bf16* Kd = Qd + N;

  int nlog = B_ * HEADS * S_ * S_;            // 73728
  zero_kernel<<<dim3(nlog / 256), 256, 0, stream>>>(logits, nlog);

  ln_kernel<<<dim3(B_ * HW_ / 128), 256, 0, stream>>>(x, ln_w, ln_b, xn);

  dim3 gG(HW_ / 256, C_ / 64, B_);            // 64 x 3 x 8 = 1536 blocks
  int dwBlocks = B_ * C_ * 8;                 // 12288

  // fused Q+K pointwise: Pq -> tmp, Pk -> A
  pw2_mfma_kernel<<<gG, 256, 0, stream>>>(xn, q_pw_w, q_pw_b, k_pw_w, k_pw_b,
                                          tmp, A);
  // fused Q+K depthwise: Qd -> d_out[0..N), Kd -> d_out[N..2N)
  dw2_kernel<<<dim3(dwBlocks, 2), 256, 0, stream>>>(
      tmp, q_dw_w, q_dw_b, Qd, A, k_dw_w, k_dw_b, Kd);
  // attention matrix (A operand = K, B operand = Q)
  gram_mfma_kernel<<<dim3(16, B_ * HEADS), 256, 0, stream>>>(Qd, Kd, logits);
  softmax_kernel<<<dim3(6), 256, 0, stream>>>(logits, alpha, att);
  // V: pw -> tmp (Pq dead), dwt -> A2 (transposed order)
  pw_mfma_kernel<false, bf16><<<gG, 256, 0, stream>>>(xn, v_pw_w, v_pw_b, nullptr, tmp);
  dwt_kernel<<<dwBlocks, 256, 0, stream>>>(tmp, v_dw_w, v_dw_b, A2);
  // att-weighted V -> A (SUBTILED; Pk dead, Qd/Kd consumed by gram already)
  av_mfma_kernel<<<dim3(HW_ / 256, B_ * HEADS), 256, 0, stream>>>(A2, att, A);
  // final projection + bias + residual(xn subtiled) -> d_out (fp32 NCHW)
  pw_mfma_kernel<true, float><<<gG, 256, 0, stream>>>(A, f_w, f_b, xn, out);
}

// Round 8
// 441.918 us; speedup vs baseline: 1.0629x; 1.0629x over previous
//
#include <hip/hip_runtime.h>
#include <hip/hip_bf16.h>

#define B_    8
#define C_    192
#define H_    128
#define W_    128
#define HW_   16384
#define HEADS 4
#define S_    48
#define EPS_  1e-5f

typedef __hip_bfloat16 bf16;
typedef unsigned short u16;
typedef __attribute__((ext_vector_type(8))) short short8;
typedef __attribute__((ext_vector_type(4))) short short4v;
typedef __attribute__((ext_vector_type(4))) float f32x4;
typedef __attribute__((ext_vector_type(8))) u16 u16x8;
typedef __attribute__((ext_vector_type(4))) u16 u16x4;
typedef __attribute__((ext_vector_type(2))) u16 u16x2;

// Subtiled bf16 layout for MFMA-consumed tensors (xn, attout):
//   element (b, c, p) at  b*C*HW + (p>>4)*3072 + (c>>3)*128 + (p&15)*8 + (c&7)
// -> an 8-channel octet at one position is 16B contiguous (direct short8
//    MFMA B-fragment); 16 lanes x 4 quads read 1KB fully coalesced.

__device__ inline float ld(const bf16* p)  { return __bfloat162float(*p); }
__device__ inline void  st(float* p, float v) { *p = v; }
__device__ inline void  st(bf16* p, float v)  { *p = __float2bfloat16(v); }
__device__ inline float b2f(u16 u) {
  unsigned v = (unsigned)u << 16;
  return __builtin_bit_cast(float, v);
}
__device__ inline u16 f2b(float f) {
  return __builtin_bit_cast(u16, __float2bfloat16(f));
}

// ---------------------------------------------------------------------------
__global__ __launch_bounds__(256) void zero_kernel(float* p, int n) {
  int i = blockIdx.x * 256 + threadIdx.x;
  if (i < n) p[i] = 0.f;
}

// ---------------------------------------------------------------------------
// LayerNorm over channel axis, one-pass, writes SUBTILED xn.
// ---------------------------------------------------------------------------
__global__ __launch_bounds__(256) void ln_kernel(
    const float* __restrict__ x, const float* __restrict__ lw,
    const float* __restrict__ lb, bf16* __restrict__ xn) {
  __shared__ float4 sS[8][32];
  __shared__ float4 sQ[8][32];
  int tid = threadIdx.x;
  int g = tid >> 5, q = tid & 31;          // channel group, position quad
  int blk = blockIdx.x;                    // 0 .. B*HW/128 - 1
  int b = blk >> 7;                        // 128 blocks per image
  int pos = (blk & 127) * 128 + q * 4;
  const float* xp = x + (size_t)b * C_ * HW_ + pos;

  float4 v[3][8];
  float s0 = 0.f, s1 = 0.f, s2 = 0.f, s3 = 0.f;
  float q0 = 0.f, q1 = 0.f, q2 = 0.f, q3 = 0.f;
#pragma unroll
  for (int t = 0; t < 3; t++)
#pragma unroll
    for (int ci = 0; ci < 8; ci++) {
      int c = t * 64 + g * 8 + ci;
      float4 f = *(const float4*)&xp[(size_t)c * HW_];
      v[t][ci] = f;
      s0 += f.x; s1 += f.y; s2 += f.z; s3 += f.w;
      q0 += f.x * f.x; q1 += f.y * f.y; q2 += f.z * f.z; q3 += f.w * f.w;
    }
  sS[g][q] = make_float4(s0, s1, s2, s3);
  sQ[g][q] = make_float4(q0, q1, q2, q3);
  __syncthreads();

  float S[4] = {}, Qs[4] = {};
#pragma unroll
  for (int gg = 0; gg < 8; gg++) {
    float4 a = sS[gg][q];
    float4 bq = sQ[gg][q];
    S[0] += a.x;  S[1] += a.y;  S[2] += a.z;  S[3] += a.w;
    Qs[0] += bq.x; Qs[1] += bq.y; Qs[2] += bq.z; Qs[3] += bq.w;
  }
  float mu[4], r[4];
#pragma unroll
  for (int i = 0; i < 4; i++) {
    mu[i] = S[i] * (1.0f / C_);
    r[i] = rsqrtf(Qs[i] * (1.0f / C_) - mu[i] * mu[i] + EPS_);
  }

  u16* base = (u16*)xn + (size_t)b * C_ * HW_ +
              (size_t)((blk & 127) * 8 + (q >> 2)) * 3072;
#pragma unroll
  for (int t = 0; t < 3; t++) {
#pragma unroll
    for (int j = 0; j < 4; j++) {
      u16x8 o8;
#pragma unroll
      for (int ci = 0; ci < 8; ci++) {
        int c = t * 64 + g * 8 + ci;
        float xv = (j == 0) ? v[t][ci].x : (j == 1) ? v[t][ci].y
                 : (j == 2) ? v[t][ci].z : v[t][ci].w;
        o8[ci] = f2b((xv - mu[j]) * r[j] * lw[c] + lb[c]);
      }
      *(u16x8*)&base[(t * 8 + g) * 128 + ((q & 3) * 4 + j) * 8] = o8;
    }
  }
}

// ---------------------------------------------------------------------------
// Pointwise conv via MFMA, SUBTILED input -> direct-global B-fragments.
// Block: 4 waves, tile 64 o x 256 pos. K=192 in 6 chunks of 32.
// B-fragments prefetched TWO chunks ahead (bf[3][4], all compile-time
// indices); only sW lives in LDS; no K-loop barriers.
// ---------------------------------------------------------------------------
#define SWR 200
template <bool RES, typename OutT>
__global__ __launch_bounds__(256) void pw_mfma_kernel(
    const bf16* __restrict__ in, const float* __restrict__ wt,
    const float* __restrict__ bias, const bf16* __restrict__ residual,
    OutT* __restrict__ out) {
  __shared__ __align__(16) u16 sW[64 * SWR];
  int tid = threadIdx.x;
  int posBase = blockIdx.x * 256;
  int oBase = blockIdx.y * 64;
  int b = blockIdx.z;
  int wv = tid >> 6, lane = tid & 63;
  int quad = lane >> 4, l15 = lane & 15;

  // ---- stage W (fp32 -> bf16), whole 64 x 192 slice, once ----
#pragma unroll
  for (int i = 0; i < 12; i++) {
    int u = (tid + i * 256) * 4;          // element index in 64x192
    int rr = u / 192, cc = u % 192;
    float4 f = *(const float4*)&wt[(size_t)(oBase + rr) * 192 + cc];
    ushort4 hv;
    hv.x = f2b(f.x); hv.y = f2b(f.y); hv.z = f2b(f.z); hv.w = f2b(f.w);
    *(ushort4*)&sW[rr * SWR + cc] = hv;
  }

  // ---- B-fragment base: subtiled (p4 = posBase>>4 + wv*4 + nt, c8 = kc*4+quad)
  const u16* xb = (const u16*)in + (size_t)b * C_ * HW_ +
                  (size_t)((posBase >> 4) + wv * 4) * 3072 + quad * 128 + l15 * 8;

  short8 bf[3][4];
#pragma unroll
  for (int nt = 0; nt < 4; nt++)
    bf[0][nt] = *(const short8*)&xb[nt * 3072];
#pragma unroll
  for (int nt = 0; nt < 4; nt++)
    bf[1][nt] = *(const short8*)&xb[nt * 3072 + 512];

  __syncthreads();                         // sW ready

  f32x4 acc[4][4] = {};
#pragma unroll
  for (int kc = 0; kc < 6; kc++) {
    if (kc < 4) {
#pragma unroll
      for (int nt = 0; nt < 4; nt++)
        bf[(kc + 2) % 3][nt] =
            *(const short8*)&xb[nt * 3072 + (kc + 2) * 512];
    }
    short8 afrag[4];
#pragma unroll
    for (int mt = 0; mt < 4; mt++)
      afrag[mt] = *(const short8*)&sW[(mt * 16 + l15) * SWR + kc * 32 + quad * 8];
#pragma unroll
    for (int nt = 0; nt < 4; nt++)
#pragma unroll
      for (int mt = 0; mt < 4; mt++)
        acc[mt][nt] = __builtin_amdgcn_mfma_f32_16x16x32_bf16(
            afrag[mt], bf[kc % 3][nt], acc[mt][nt], 0, 0, 0);
  }

  // ---- epilogue: D row = quad*4 + reg, col = l15; NCHW output ----
  // residual (subtiled): (o>>3) = oBase/8 + mt*2 + (quad>>1),
  // (o&7) = (quad&1)*4 + r  -> 4 consecutive r = one u16x4 load.
  const u16* rb = nullptr;
  if (RES)
    rb = (const u16*)residual + (size_t)b * C_ * HW_ +
         (size_t)((posBase >> 4) + wv * 4) * 3072 + l15 * 8;
#pragma unroll
  for (int mt = 0; mt < 4; mt++) {
#pragma unroll
    for (int nt = 0; nt < 4; nt++) {
      u16x4 r4 = {};
      if (RES)
        r4 = *(const u16x4*)&rb[nt * 3072 +
                                ((oBase >> 3) + mt * 2 + (quad >> 1)) * 128 +
                                (quad & 1) * 4];
#pragma unroll
      for (int r = 0; r < 4; r++) {
        int o = oBase + mt * 16 + quad * 4 + r;
        int p = posBase + wv * 64 + nt * 16 + l15;
        float val = acc[mt][nt][r] + bias[o];
        if (RES) val += b2f(r4[r]);
        st(out + ((size_t)b * C_ + o) * HW_ + p, val);
      }
    }
  }
}

// ---------------------------------------------------------------------------
// Depthwise 3x3, SAME zero pad. LDS-tiled: block = one (b,c), 16 rows x 128.
// Used for Q and K (output order = input order; gram is pos-order-invariant).
// ---------------------------------------------------------------------------
__global__ __launch_bounds__(256) void dw_kernel(
    const bf16* __restrict__ in, const float* __restrict__ w9,
    const float* __restrict__ bias, bf16* __restrict__ out) {
  __shared__ __align__(16) u16 sT[18 * 128];
  int blk = blockIdx.x;                 // B*C*8
  int bc = blk >> 3;
  int h0 = (blk & 7) * 16;
  int c = bc % C_;
  const u16* ip = (const u16*)in + (size_t)bc * HW_;
  int tid = threadIdx.x;

  for (int ch = tid; ch < 288; ch += 256) {
    int r = ch >> 4, g = ch & 15;
    int gh = h0 - 1 + r;
    u16x8 val = {};
    if (gh >= 0 && gh < H_) val = *(const u16x8*)&ip[gh * 128 + g * 8];
    *(u16x8*)&sT[r * 128 + g * 8] = val;
  }
  __syncthreads();

  int r_o = tid >> 4, g = tid & 15;
  const float* wp = w9 + c * 9;
  float acc[8];
#pragma unroll
  for (int j = 0; j < 8; j++) acc[j] = bias[c];
#pragma unroll
  for (int k = 0; k < 3; k++) {
    int rr = r_o + k;
    u16x8 mid = *(const u16x8*)&sT[rr * 128 + g * 8];
    float m[8];
#pragma unroll
    for (int j = 0; j < 8; j++) m[j] = b2f(mid[j]);
    float lv = g ? b2f(sT[rr * 128 + g * 8 - 1]) : 0.f;
    float rv = (g < 15) ? b2f(sT[rr * 128 + g * 8 + 8]) : 0.f;
    float wl = wp[k * 3], wc = wp[k * 3 + 1], wr = wp[k * 3 + 2];
#pragma unroll
    for (int j = 0; j < 8; j++) {
      float left  = (j == 0) ? lv : m[j - 1];
      float right = (j == 7) ? rv : m[j + 1];
      acc[j] += wl * left + wc * m[j] + wr * right;
    }
  }
  u16x8 o;
#pragma unroll
  for (int j = 0; j < 8; j++) o[j] = f2b(acc[j]);
  *(u16x8*)((u16*)out + (size_t)bc * HW_ + (h0 + r_o) * 128 + g * 8) = o;
}

// ---------------------------------------------------------------------------
// Depthwise 3x3 with TRANSPOSED spatial output: out[bc, w*H + h] = conv(h,w).
// Used for V only (makes attout land in final order; transpose deleted).
// ---------------------------------------------------------------------------
__global__ __launch_bounds__(256) void dwt_kernel(
    const bf16* __restrict__ in, const float* __restrict__ w9,
    const float* __restrict__ bias, bf16* __restrict__ out) {
  __shared__ __align__(16) u16 sIn[130 * 32];
  int blk = blockIdx.x;                 // B*C*8
  int bc = blk >> 3;
  int w0 = (blk & 7) * 16;
  int c = bc % C_;
  const u16* ip = (const u16*)in + (size_t)bc * HW_;
  int tid = threadIdx.x;

  for (int idx = tid; idx < 520; idx += 256) {
    int r = idx >> 2, seg = idx & 3;
    int h = r - 1;
    int w = w0 - 8 + seg * 8;
    u16x8 val = {};
    if (h >= 0 && h < H_ && w >= 0 && w < W_)
      val = *(const u16x8*)&ip[h * W_ + w];
    int colp = (seg * 8) ^ (((r >> 3) & 3) << 4);
    *(u16x8*)&sIn[r * 32 + colp] = val;
  }
  __syncthreads();

  int wl = tid & 15, ho = tid >> 4;     // w = w0+wl, h = ho*8 .. ho*8+7
  const float* wp = w9 + c * 9;
  float wk[9];
#pragma unroll
  for (int i = 0; i < 9; i++) wk[i] = wp[i];
  float bs = bias[c];
  float acc[8];
#pragma unroll
  for (int j = 0; j < 8; j++) acc[j] = bs;
#pragma unroll
  for (int k = 0; k < 10; k++) {
    int r = ho * 8 + k;                 // staged row = input h + 1
    int swz = ((r >> 3) & 3) << 4;
    float lv = b2f(sIn[r * 32 + ((wl + 7) ^ swz)]);
    float mv = b2f(sIn[r * 32 + ((wl + 8) ^ swz)]);
    float rv = b2f(sIn[r * 32 + ((wl + 9) ^ swz)]);
#pragma unroll
    for (int kh = 0; kh < 3; kh++) {
      int j = k - kh;                   // output row index
      if (j >= 0 && j < 8)
        acc[j] += wk[kh * 3] * lv + wk[kh * 3 + 1] * mv + wk[kh * 3 + 2] * rv;
    }
  }
  u16x8 o;
#pragma unroll
  for (int j = 0; j < 8; j++) o[j] = f2b(acc[j]);
  *(u16x8*)((u16*)out + (size_t)bc * HW_ + (w0 + wl) * H_ + ho * 8) = o;
}

// ---------------------------------------------------------------------------
// Gram via MFMA, no LDS staging (pos contiguous for both operands).
// logits[bh][sk][sq] = sum_pos K[sk,pos]*Q[sq,pos]
// ---------------------------------------------------------------------------
__global__ __launch_bounds__(256) void gram_mfma_kernel(
    const bf16* __restrict__ Q, const bf16* __restrict__ K,
    float* __restrict__ logits) {
  __shared__ float sP[4][S_ * S_];
  int bh = blockIdx.y;
  int b = bh >> 2, hd = bh & 3;
  int tid = threadIdx.x;
  int wv = tid >> 6, lane = tid & 63;
  int quad = lane >> 4, l15 = lane & 15;
  const u16* Qb = (const u16*)Q + ((size_t)b * C_ + hd * S_) * HW_;
  const u16* Kb = (const u16*)K + ((size_t)b * C_ + hd * S_) * HW_;
  int pbase = blockIdx.x * 1024 + wv * 256 + quad * 8;

  f32x4 acc[3][3] = {};
#pragma unroll
  for (int t = 0; t < 8; t++) {
    int p = pbase + t * 32;
    short8 a[3], bb[3];
#pragma unroll
    for (int mi = 0; mi < 3; mi++)
      a[mi] = *(const short8*)&Kb[(size_t)(mi * 16 + l15) * HW_ + p];
#pragma unroll
    for (int ni = 0; ni < 3; ni++)
      bb[ni] = *(const short8*)&Qb[(size_t)(ni * 16 + l15) * HW_ + p];
#pragma unroll
    for (int mi = 0; mi < 3; mi++)
#pragma unroll
      for (int ni = 0; ni < 3; ni++)
        acc[mi][ni] = __builtin_amdgcn_mfma_f32_16x16x32_bf16(
            a[mi], bb[ni], acc[mi][ni], 0, 0, 0);
  }

#pragma unroll
  for (int mi = 0; mi < 3; mi++)
#pragma unroll
    for (int r = 0; r < 4; r++) {
      int sk = mi * 16 + quad * 4 + r;
#pragma unroll
      for (int ni = 0; ni < 3; ni++)
        sP[wv][sk * S_ + ni * 16 + l15] = acc[mi][ni][r];
    }
  __syncthreads();

  float* lp = logits + (size_t)bh * S_ * S_;
  for (int e = tid; e < S_ * S_; e += 256)
    atomicAdd(&lp[e], sP[0][e] + sP[1][e] + sP[2][e] + sP[3][e]);
}

// ---------------------------------------------------------------------------
// Softmax over last axis (sq), one thread per (b,hd,sk) row.
// ---------------------------------------------------------------------------
__global__ __launch_bounds__(256) void softmax_kernel(
    const float* __restrict__ logits, const float* __restrict__ alpha,
    float* __restrict__ att) {
  int row = blockIdx.x * 256 + threadIdx.x;   // 0..1535
  if (row >= B_ * HEADS * S_) return;
  float inv_a = 1.0f / alpha[0];
  const float* lp = logits + (size_t)row * S_;
  float v[S_];
  float m = -1e30f;
  for (int i = 0; i < S_; i++) {
    v[i] = lp[i] * inv_a;
    m = fmaxf(m, v[i]);
  }
  float s = 0.f;
  for (int i = 0; i < S_; i++) { v[i] = expf(v[i] - m); s += v[i]; }
  float inv_s = 1.0f / s;
  float* ap = att + (size_t)row * S_;
  for (int i = 0; i < S_; i++) ap[i] = v[i] * inv_s;
}

// ---------------------------------------------------------------------------
// att-weighted V via MFMA; output written SUBTILED (final-pw input layout).
// ---------------------------------------------------------------------------
#define AVP 264   // sV pitch in u16 (multiple of 8 -> 16B-aligned rows)
#define ATP 72    // sAtt pitch in u16 (144B rows, 16B aligned)
__global__ __launch_bounds__(256) void av_mfma_kernel(
    const bf16* __restrict__ V, const float* __restrict__ att,
    bf16* __restrict__ out) {
  __shared__ __align__(16) u16 sV[64 * AVP];   // [s 0..63][pos 0..255]
  __shared__ __align__(16) u16 sA[48 * ATP];   // [q 0..47][s 0..63]
  int bh = blockIdx.y;
  int b = bh >> 2, hd = bh & 3;
  int p0 = blockIdx.x * 256;
  int tid = threadIdx.x;
  int wv = tid >> 6, lane = tid & 63;
  int quad = lane >> 4, l15 = lane & 15;
  const u16* Vb = (const u16*)V + ((size_t)b * C_ + hd * S_) * HW_ + p0;
  const float* ap = att + (size_t)bh * S_ * S_;

#pragma unroll
  for (int i = 0; i < 6; i++) {
    int e = tid + i * 256;               // 0..1535 over 48 s x 32 pos-octets
    int s = e >> 5, p8 = (e & 31) * 8;
    u16x8 v8 = *(const u16x8*)&Vb[(size_t)s * HW_ + p8];
    *(u16x8*)&sV[s * AVP + p8] = v8;
  }
  {
    unsigned* zp = (unsigned*)&sV[48 * AVP];
    for (int e = tid; e < 16 * AVP / 2; e += 256) zp[e] = 0;
  }
  for (int e = tid; e < S_ * S_; e += 256) {
    int q = e % S_, s = e / S_;          // ap[s*48+q] == ap[e]
    sA[q * ATP + s] = f2b(ap[e]);
  }
  for (int e = tid; e < S_ * 16; e += 256) {
    int q = e >> 4, s = 48 + (e & 15);
    sA[q * ATP + s] = 0;
  }
  __syncthreads();

  f32x4 acc[3][4] = {};
#pragma unroll
  for (int kc = 0; kc < 2; kc++) {
    short8 afrag[3];
#pragma unroll
    for (int mt = 0; mt < 3; mt++)
      afrag[mt] = *(const short8*)&sA[(mt * 16 + l15) * ATP + kc * 32 + quad * 8];
#pragma unroll
    for (int nt = 0; nt < 4; nt++) {
      int p = wv * 64 + nt * 16 + l15;
      short8 bfrag;
#pragma unroll
      for (int j = 0; j < 8; j++)
        bfrag[j] = (short)sV[(kc * 32 + quad * 8 + j) * AVP + p];
#pragma unroll
      for (int mt = 0; mt < 3; mt++)
        acc[mt][nt] = __builtin_amdgcn_mfma_f32_16x16x32_bf16(
            afrag[mt], bfrag, acc[mt][nt], 0, 0, 0);
    }
  }

  u16* ob = (u16*)out + (size_t)b * C_ * HW_ + (size_t)(p0 >> 4) * 3072;
#pragma unroll
  for (int mt = 0; mt < 3; mt++)
#pragma unroll
    for (int r = 0; r < 4; r++) {
      int ql = mt * 16 + quad * 4 + r;
      int ch = hd * S_ + ql;
      int cb = (ch >> 3) * 128 + (ch & 7);
#pragma unroll
      for (int nt = 0; nt < 4; nt++)
        ob[(size_t)(wv * 4 + nt) * 3072 + cb + l15 * 8] = f2b(acc[mt][nt][r]);
    }
}

// ---------------------------------------------------------------------------
extern "C" void kernel_launch(void* const* d_in, const int* in_sizes, int n_in,
                              void* d_out, int out_size, void* d_ws, size_t ws_size,
                              hipStream_t stream) {
  const float* x      = (const float*)d_in[0];
  const float* ln_w   = (const float*)d_in[1];
  const float* ln_b   = (const float*)d_in[2];
  const float* q_pw_w = (const float*)d_in[3];
  const float* q_pw_b = (const float*)d_in[4];
  const float* q_dw_w = (const float*)d_in[5];
  const float* q_dw_b = (const float*)d_in[6];
  const float* k_pw_w = (const float*)d_in[7];
  const float* k_pw_b = (const float*)d_in[8];
  const float* k_dw_w = (const float*)d_in[9];
  const float* k_dw_b = (const float*)d_in[10];
  const float* v_pw_w = (const float*)d_in[11];
  const float* v_pw_b = (const float*)d_in[12];
  const float* v_dw_w = (const float*)d_in[13];
  const float* v_dw_b = (const float*)d_in[14];
  const float* f_w    = (const float*)d_in[15];
  const float* f_b    = (const float*)d_in[16];
  const float* alpha  = (const float*)d_in[17];
  float* out = (float*)d_out;

  size_t N = (size_t)B_ * C_ * HW_;           // 25,165,824
  bf16* xn   = (bf16*)d_ws;                   // LayerNorm output, SUBTILED
  bf16* tmp  = xn + N;                        // pw outputs (NCHW) / attout (SUBTILED)
  bf16* A    = tmp + N;                        // Q, then V (V in transposed order)
  float* logits = (float*)(A + N);            // [32][48][48]
  float* att    = logits + (size_t)B_ * HEADS * S_ * S_;
  bf16* Kb     = (bf16*)d_out;                // d_out as scratch for K

  int nlog = B_ * HEADS * S_ * S_;            // 73728
  zero_kernel<<<dim3(nlog / 256), 256, 0, stream>>>(logits, nlog);

  ln_kernel<<<dim3(B_ * HW_ / 128), 256, 0, stream>>>(x, ln_w, ln_b, xn);

  dim3 gG(HW_ / 256, C_ / 64, B_);            // 64 x 3 x 8 = 1536 blocks
  int dwBlocks = B_ * C_ * 8;                 // 12288

  // Q
  pw_mfma_kernel<false, bf16><<<gG, 256, 0, stream>>>(xn, q_pw_w, q_pw_b, nullptr, tmp);
  dw_kernel<<<dwBlocks, 256, 0, stream>>>(tmp, q_dw_w, q_dw_b, A);
  // K -> d_out scratch
  pw_mfma_kernel<false, bf16><<<gG, 256, 0, stream>>>(xn, k_pw_w, k_pw_b, nullptr, tmp);
  dw_kernel<<<dwBlocks, 256, 0, stream>>>(tmp, k_dw_w, k_dw_b, Kb);
  // attention matrix (A operand = K, B operand = Q)
  gram_mfma_kernel<<<dim3(16, B_ * HEADS), 256, 0, stream>>>(A, Kb, logits);
  softmax_kernel<<<dim3(6), 256, 0, stream>>>(logits, alpha, att);
  // V (depthwise writes spatially transposed -> attout lands in final order)
  pw_mfma_kernel<false, bf16><<<gG, 256, 0, stream>>>(xn, v_pw_w, v_pw_b, nullptr, tmp);
  dwt_kernel<<<dwBlocks, 256, 0, stream>>>(tmp, v_dw_w, v_dw_b, A);
  // att-weighted V via MFMA -> tmp (SUBTILED, final-pw input layout)
  av_mfma_kernel<<<dim3(HW_ / 256, B_ * HEADS), 256, 0, stream>>>(A, att, tmp);
  // final projection + bias + residual(xn subtiled) -> d_out (fp32 NCHW)
  pw_mfma_kernel<true, float><<<gG, 256, 0, stream>>>(tmp, f_w, f_b, xn, out);
}